// Round 3
// baseline (420.839 us; speedup 1.0000x reference)
//
#include <hip/hip_runtime.h>

typedef _Float16 f16x8 __attribute__((ext_vector_type(8)));
typedef _Float16 f16x4 __attribute__((ext_vector_type(4)));
typedef float f32x4 __attribute__((ext_vector_type(4)));

#define DEVI __device__ __forceinline__

constexpr int NROWS = 2048;
constexpr int HEADP = 20224;   // 79*256 (20002 padded)
constexpr int NCBH  = 79;
constexpr int PSTH  = 80;
constexpr int VT    = 40000;
constexpr int VTP   = 40192;   // 157*256
constexpr int NCBT  = 157;
constexpr int PSTT  = 160;

DEVI void glds16(const void* g, void* l) {
  __builtin_amdgcn_global_load_lds((const __attribute__((address_space(1))) unsigned int*)g,
                                   (__attribute__((address_space(3))) unsigned int*)l,
                                   16, 0, 0);
}

#define VMW(N) asm volatile("s_waitcnt vmcnt(" #N ")" ::: "memory")
#define LGKM0  asm volatile("s_waitcnt lgkmcnt(0)" ::: "memory")
#define SCB    __builtin_amdgcn_sched_barrier(0)
#define BARR   __builtin_amdgcn_s_barrier()
#define PR1 __builtin_amdgcn_s_setprio(1)
#define PR0 __builtin_amdgcn_s_setprio(0)

// ---------------- prep: per-row label info + compaction lists ----------------
__global__ void prep_kernel(const int* __restrict__ x, const int* __restrict__ labels,
                            int* cl, int* headcol, int* tailpos, int* pos1, int* pos2,
                            int* L1, int* L2, int* T0, int* T1, int* T2, int* counts)
{
  __shared__ int sc[3][256];
  int tid = threadIdx.x;
  int base = tid * 8;
  int lcl[8]; int c1 = 0, c2 = 0;
  for (int j = 0; j < 8; j++) {
    int l = labels[base + j];
    int c = l < 20000 ? 0 : (l < 60000 ? 1 : 2);
    lcl[j] = c;
    cl[base + j] = c;
    headcol[base + j] = c == 0 ? l : (c == 1 ? 20001 : 20000);
    tailpos[base + j] = c == 1 ? l - 20000 : (c == 2 ? l - 60000 : 0);
    if (c == 1) c1++; else if (c == 2) c2++;
  }
  sc[1][tid] = c1; sc[2][tid] = c2;
  __syncthreads();
  for (int d = 1; d < 256; d <<= 1) {
    int v1 = tid >= d ? sc[1][tid - d] : 0;
    int v2 = tid >= d ? sc[2][tid - d] : 0;
    __syncthreads();
    sc[1][tid] += v1; sc[2][tid] += v2;
    __syncthreads();
  }
  int o1 = sc[1][tid] - c1, o2 = sc[2][tid] - c2;
  int cnt1 = sc[1][255], cnt2 = sc[2][255];
  for (int j = 0; j < 8; j++) {
    int n = base + j; int c = lcl[j];
    if (c == 1)      { pos1[n] = o1; L1[o1] = n; o1++; pos2[n] = 0; }
    else if (c == 2) { pos2[n] = o2; L2[o2] = n; o2++; pos1[n] = 0; }
    else             { pos1[n] = 0; pos2[n] = 0; }
  }
  for (int i = cnt1 + tid; i < NROWS; i += 256) L1[i] = 0;
  for (int i = cnt2 + tid; i < NROWS; i += 256) L2[i] = 0;
  if (tid == 0) { counts[0] = cnt1; counts[1] = cnt2; }
  __syncthreads();
  int tcl[8]; int t0 = 0, t1 = 0, t2 = 0;
  for (int j = 0; j < 8; j++) {
    int t = x[base + j];
    int c = t < 20000 ? 0 : (t < 60000 ? 1 : 2);
    tcl[j] = c;
    if (c == 0) t0++; else if (c == 1) t1++; else t2++;
  }
  sc[0][tid] = t0; sc[1][tid] = t1; sc[2][tid] = t2;
  __syncthreads();
  for (int d = 1; d < 256; d <<= 1) {
    int v0 = tid >= d ? sc[0][tid - d] : 0;
    int v1 = tid >= d ? sc[1][tid - d] : 0;
    int v2 = tid >= d ? sc[2][tid - d] : 0;
    __syncthreads();
    sc[0][tid] += v0; sc[1][tid] += v1; sc[2][tid] += v2;
    __syncthreads();
  }
  int q0 = sc[0][tid] - t0, q1 = sc[1][tid] - t1, q2 = sc[2][tid] - t2;
  int tc0 = sc[0][255], tc1 = sc[1][255], tc2 = sc[2][255];
  for (int j = 0; j < 8; j++) {
    int n = base + j; int c = tcl[j];
    if (c == 0) T0[q0++] = n;
    else if (c == 1) T1[q1++] = n;
    else T2[q2++] = n;
  }
  for (int i = tc0 + tid; i < NROWS; i += 256) T0[i] = 0;
  for (int i = tc1 + tid; i < NROWS; i += 256) T1[i] = 0;
  for (int i = tc2 + tid; i < NROWS; i += 256) T2[i] = 0;
  if (tid == 0) { counts[2] = tc0; counts[3] = tc1; counts[4] = tc2; }
}

// ---------------- fused pack / convert / transpose ----------------
constexpr int PB0 = HEADP;            // headw  (20224)
constexpr int PB1 = PB0 + VTP / 4;    // w1p    (+10048)
constexpr int PB2 = PB1 + VTP / 8;    // w2p    (+5024)
constexpr int PB3 = PB2 + 1024;       // ep0f
constexpr int PB4 = PB3 + 256;        // ep1f
constexpr int PB5 = PB4 + 64;         // ep2f
constexpr int PB6 = PB5 + 1024;       // op0T (32x32)
constexpr int PB7 = PB6 + 256;        // op1T (8x32)
constexpr int PB8 = PB7 + 128;        // op2T (4x32)

DEVI void cvt_f16(const float* src, _Float16* dst, int vb, int tid) {
  int g = vb * 256 + tid;
  float4 v = *(const float4*)(src + (size_t)g * 4);
  f16x4 o = {(_Float16)v.x, (_Float16)v.y, (_Float16)v.z, (_Float16)v.w};
  *(f16x4*)(dst + (size_t)g * 4) = o;
}

DEVI void tr32(const float* in, _Float16* out, int C, int bx, int by, int tid) {
  __shared__ float tile[32][33];
  int c0 = bx * 32, r0 = by * 32;
  int tx = tid & 31, ty = tid >> 5;          // (32, 8)
  for (int i = 0; i < 4; i++) {
    int c = c0 + tx; int r = r0 + ty + i * 8;
    tile[ty + i * 8][tx] = (c < C) ? in[(size_t)r * C + c] : 0.f;
  }
  __syncthreads();
  for (int i = 0; i < 4; i++)
    out[(size_t)(c0 + ty + i * 8) * 1024 + r0 + tx] = (_Float16)tile[tx][ty + i * 8];
}

__global__ void fused_pack(const float* __restrict__ out_w0, const float* __restrict__ out_b0,
                           const float* __restrict__ cluster_w, const float* __restrict__ cluster_b,
                           const float* __restrict__ out_w1, const float* __restrict__ out_b1,
                           const float* __restrict__ out_w2, const float* __restrict__ out_b2,
                           const float* __restrict__ emb_proj0, const float* __restrict__ emb_proj1,
                           const float* __restrict__ emb_proj2,
                           const float* __restrict__ out_proj0, const float* __restrict__ out_proj1,
                           const float* __restrict__ out_proj2,
                           _Float16* headw, float* headb,
                           _Float16* w1p, float* b1p, _Float16* w2p, float* b2p,
                           _Float16* ep0f, _Float16* ep1f, _Float16* ep2f,
                           _Float16* op0T, _Float16* op1T, _Float16* op2T)
{
  int bid = blockIdx.x, tid = threadIdx.x;
  if (bid < PB0) {
    int g = bid * 256 + tid;
    int r = g >> 8, k4 = (g & 255) << 2;
    float4 v = {0.f, 0.f, 0.f, 0.f};
    if (r < 20000)      v = *(const float4*)(out_w0 + ((size_t)r << 10) + k4);
    else if (r < 20002) v = *(const float4*)(cluster_w + ((size_t)(r - 20000) << 10) + k4);
    f16x4 o = {(_Float16)v.x, (_Float16)v.y, (_Float16)v.z, (_Float16)v.w};
    *(f16x4*)(headw + ((size_t)r << 10) + k4) = o;
    if (g < HEADP) headb[g] = g < 20000 ? out_b0[g] : (g < 20002 ? cluster_b[g - 20000] : -1e30f);
  } else if (bid < PB1) {
    int g = (bid - PB0) * 256 + tid;          // VTP*64
    int r = g >> 6, k4 = (g & 63) << 2;
    float4 v = {0.f, 0.f, 0.f, 0.f};
    if (r < VT) v = *(const float4*)(out_w1 + ((size_t)r << 8) + k4);
    f16x4 o = {(_Float16)v.x, (_Float16)v.y, (_Float16)v.z, (_Float16)v.w};
    *(f16x4*)(w1p + ((size_t)r << 8) + k4) = o;
    if (g < VTP) b1p[g] = g < VT ? out_b1[g] : -1e30f;
  } else if (bid < PB2) {
    int g = (bid - PB1) * 256 + tid;          // VTP*32 (Eout=128, Ein=64)
    int r = g >> 5, k4 = (g & 31) << 2;
    float4 v = {0.f, 0.f, 0.f, 0.f};
    if (r < VT && k4 < 64) v = *(const float4*)(out_w2 + ((size_t)r << 6) + k4);
    f16x4 o = {(_Float16)v.x, (_Float16)v.y, (_Float16)v.z, (_Float16)v.w};
    *(f16x4*)(w2p + ((size_t)r << 7) + k4) = o;
    if (g < VTP) b2p[g] = g < VT ? b2p[g] * 0.f + out_b2[g] : -1e30f;
  } else if (bid < PB3) { cvt_f16(emb_proj0, ep0f, bid - PB2, tid); }
  else if (bid < PB4) { cvt_f16(emb_proj1, ep1f, bid - PB3, tid); }
  else if (bid < PB5) { cvt_f16(emb_proj2, ep2f, bid - PB4, tid); }
  else if (bid < PB6) { int l = bid - PB5; tr32(out_proj0, op0T, 1024, l & 31, l >> 5, tid); }
  else if (bid < PB7) { int l = bid - PB6; tr32(out_proj1, op1T, 256, l & 7, l >> 3, tid); }
  else                { int l = bid - PB7; tr32(out_proj2, op2T, 64, l & 3, l >> 2, tid); }
}

// ---------------- fused gather ----------------
DEVI void gat(const float* emb, const int* x, const int* list, _Float16* dst,
              int tbase, int vmax, int log2E, int vb, int tid) {
  int g = vb * 256 + tid;
  int r = g >> (log2E - 2);
  int e4 = (g & ((1 << (log2E - 2)) - 1)) << 2;
  int n = list[r];
  int tl = x[n] - tbase;
  tl = tl < 0 ? 0 : (tl >= vmax ? vmax - 1 : tl);
  float4 v = *(const float4*)(emb + ((size_t)tl << log2E) + e4);
  f16x4 o = {(_Float16)(v.x * 32.f), (_Float16)(v.y * 32.f),
             (_Float16)(v.z * 32.f), (_Float16)(v.w * 32.f)};
  *(f16x4*)(dst + ((size_t)r << log2E) + e4) = o;
}

__global__ void fused_gather(const float* __restrict__ emb_w0, const float* __restrict__ emb_w1,
                             const float* __restrict__ emb_w2, const int* __restrict__ x,
                             const int* __restrict__ T0, const int* __restrict__ T1,
                             const int* __restrict__ T2,
                             _Float16* E0, _Float16* E1, _Float16* E2)
{
  int bid = blockIdx.x, tid = threadIdx.x;
  if (bid < 2048)      gat(emb_w0, x, T0, E0, 0, 20000, 10, bid, tid);
  else if (bid < 2560) gat(emb_w1, x, T1, E1, 20000, 40000, 8, bid - 2048, tid);
  else                 gat(emb_w2, x, T2, E2, 60000, 40000, 6, bid - 2560, tid);
}

// ---------------- 128-tile GEMM (for small hidden/proj stages) ----------------
__global__ __launch_bounds__(256)
void gemm128(const _Float16* __restrict__ A, int lda,
             const _Float16* __restrict__ Wm, int ldw,
             _Float16* __restrict__ C, int ldc, int Nvalid,
             const int* __restrict__ amap, const int* __restrict__ cmap,
             const int* __restrict__ cnt, int K)
{
  int rb = blockIdx.x, cb = blockIdx.y;
  int valid = cnt ? *cnt : NROWS;
  if (cnt && rb * 128 >= valid) return;
  __shared__ __attribute__((aligned(16))) _Float16 As[128 * 32];
  __shared__ __attribute__((aligned(16))) _Float16 Ws[128 * 32];
  int tid = threadIdx.x;
  int lane = tid & 63, wid = tid >> 6;
  int wr = wid >> 1, wc = wid & 1;
  int sr = wid * 32 + (lane >> 2);
  int arow0 = rb * 128 + sr, arow1 = arow0 + 16;
  if (amap) { arow0 = amap[arow0]; arow1 = amap[arow1]; }
  int ko = (lane & 3) * 8;
  const _Float16* ag0 = A + (size_t)arow0 * lda + ko;
  const _Float16* ag1 = A + (size_t)arow1 * lda + ko;
  const _Float16* wg0 = Wm + (size_t)(cb * 128 + sr) * ldw + ko;
  const _Float16* wg1 = wg0 + (size_t)16 * ldw;
  _Float16* as0 = As + (wid * 32) * 32;
  _Float16* as1 = as0 + 16 * 32;
  _Float16* ws0 = Ws + (wid * 32) * 32;
  _Float16* ws1 = ws0 + 16 * 32;
  f32x4 acc[4][4] = {};
  int lr = lane & 15, lk = (lane >> 4) * 8;
  const int nk = K >> 5;
  for (int kt = 0; kt < nk; ++kt) {
    int kofs = kt * 32;
    glds16(ag0 + kofs, as0);
    glds16(ag1 + kofs, as1);
    glds16(wg0 + kofs, ws0);
    glds16(wg1 + kofs, ws1);
    __syncthreads();
    f16x8 af[4], bf[4];
    #pragma unroll
    for (int mi = 0; mi < 4; mi++)
      af[mi] = *(const f16x8*)(As + (wr * 64 + mi * 16 + lr) * 32 + lk);
    #pragma unroll
    for (int ni = 0; ni < 4; ni++)
      bf[ni] = *(const f16x8*)(Ws + (wc * 64 + ni * 16 + lr) * 32 + lk);
    #pragma unroll
    for (int mi = 0; mi < 4; mi++)
      #pragma unroll
      for (int ni = 0; ni < 4; ni++)
        acc[mi][ni] = __builtin_amdgcn_mfma_f32_16x16x32_f16(af[mi], bf[ni], acc[mi][ni], 0, 0, 0);
    __syncthreads();
  }
  #pragma unroll
  for (int mi = 0; mi < 4; mi++) {
    #pragma unroll
    for (int j = 0; j < 4; j++) {
      int rl = wr * 64 + mi * 16 + (lane >> 4) * 4 + j;
      int rg = rb * 128 + rl;
      if (rg >= valid) continue;
      int orow = cmap ? cmap[rg] : rg;
      #pragma unroll
      for (int ni = 0; ni < 4; ni++) {
        int col = cb * 128 + wc * 64 + ni * 16 + (lane & 15);
        if (col < Nvalid) C[(size_t)orow * ldc + col] = (_Float16)acc[mi][ni][j];
      }
    }
  }
}

// ---------------- 256-tile quadrant-phase GEMM + online-LSE epilogue ----------------
DEVI void rd4(f16x8 (&v)[4], const _Float16* p) {
  #pragma unroll
  for (int i = 0; i < 4; i++) v[i] = *(const f16x8*)(p + i * 512);
}
template<int BASE>
DEVI void cl16(f32x4 (&acc)[8][4], const f16x8 (&a)[4], const f16x8 (&b)[4]) {
  #pragma unroll
  for (int mi = 0; mi < 4; ++mi)
    #pragma unroll
    for (int nb = 0; nb < 4; ++nb)
      acc[BASE + mi][nb] = __builtin_amdgcn_mfma_f32_16x16x32_f16(a[mi], b[nb], acc[BASE + mi][nb], 0, 0, 0);
}
DEVI void stg2(const _Float16* g0, const _Float16* g1, _Float16* l) {
  glds16(g0, l);
  glds16(g1, l + 4096);
}

__global__ __launch_bounds__(512, 1)
void gemm_lse(const _Float16* __restrict__ A, int lda,
              const _Float16* __restrict__ Wm, int ldw,
              const float* __restrict__ bias,
              const int* __restrict__ cnt,
              float* __restrict__ pm, float* __restrict__ ps,
              int pstride, int K, int nrb)
{
  __shared__ __attribute__((aligned(16))) _Float16 lds[65536];   // 128 KiB
  _Float16* lA = lds;
  _Float16* lB = lds + 32768;
  // regions R(p,s) at offset p*16384 + s*8192 f16 ([256 rows][32 k] each, swizzled)

  int bid = blockIdx.x;
  int qq = gridDim.x >> 3;                 // grid divisible by 8
  int w = (bid & 7) * qq + (bid >> 3);     // XCD-contiguous cb panels
  int rb = w % nrb, cb = w / nrb;
  int valid = cnt ? *cnt : NROWS;
  if (rb * 256 >= valid) return;

  int tid = threadIdx.x;
  int lane = tid & 63, wid = tid >> 6;
  int wr = wid >> 2, wc = wid & 3;
  int lr = lane & 15;

  // staging: thread covers 16B chunk q0 (rows 0-127) / q0+512 (rows 128-255); src pre-swizzled
  int q0 = wid * 64 + lane;
  int r0 = q0 >> 2;
  int scol = (((lane & 3) ^ ((q0 >> 3) & 3)) << 3);
  const _Float16* pA0 = A + (size_t)(rb * 256 + r0) * lda + scol;
  const _Float16* pA1 = pA0 + (size_t)128 * lda;
  const _Float16* pB0 = Wm + (size_t)(cb * 256 + r0) * ldw + scol;
  const _Float16* pB1 = pB0 + (size_t)128 * ldw;
  int sdA = wid * 512;

  // fragment read bases (swizzled slot)
  int slotf = (((lane >> 4) ^ ((lr >> 1) & 3)) << 3);
  int laneA = (wr * 128 + lr) * 32 + slotf;
  int laneB = (wc * 64 + lr) * 32 + slotf;

  f32x4 acc[8][4] = {};
  f16x8 af[4], ag[4], bf[4];

  const int nk = K >> 6;                   // K-tiles of 64, nk >= 2

  // prologue: stage A0(0) B0(0) A1(0) B1(0) A0(1) B0(1); drain tile 0 (vmcnt(4))
  asm volatile("s_waitcnt vmcnt(0) lgkmcnt(0)" ::: "memory");
  stg2(pA0,      pA1,      lA + sdA);              // A0(0) -> RA(0,0)
  stg2(pB0,      pB1,      lB + sdA);              // B0(0) -> RB(0,0)
  stg2(pA0 + 32, pA1 + 32, lA + 8192 + sdA);       // A1(0) -> RA(0,1)
  stg2(pB0 + 32, pB1 + 32, lB + 8192 + sdA);       // B1(0) -> RB(0,1)
  {
    int k1 = (nk > 1 ? 64 : 0);
    stg2(pA0 + k1, pA1 + k1, lA + 16384 + sdA);    // A0(1) -> RA(1,0)
    stg2(pB0 + k1, pB1 + k1, lB + 16384 + sdA);    // B0(1) -> RB(1,0)
  }
  VMW(4); SCB; BARR; SCB;

  for (int t = 0; t < nk; ++t) {
    int p = (t & 1) * 16384;
    int q = 16384 - p;
    _Float16* A0 = lA + p;            // RA(p,0): tile t ks0
    _Float16* A1 = lA + p + 8192;     // RA(p,1): tile t ks1
    _Float16* B0 = lB + p;
    _Float16* B1 = lB + p + 8192;
    int ko1 = ((t + 1 < nk) ? t + 1 : nk - 1) * 64;   // clamped stage cols
    int ko2 = ((t + 2 < nk) ? t + 2 : nk - 1) * 64;

    // ---- P1: quadrant (Mh0, ks0) — 8 reads, stage A1(t+1)
    rd4(af, A0 + laneA);
    rd4(bf, B0 + laneB);
    stg2(pA0 + ko1 + 32, pA1 + ko1 + 32, lA + q + 8192 + sdA);
    SCB; BARR; LGKM0; SCB;
    PR1; cl16<0>(acc, af, bf); PR0;
    SCB; BARR; SCB;

    // ---- P2: quadrant (Mh1, ks0) — 4 reads (bf reused), stage B1(t+1)
    rd4(ag, A0 + laneA + 2048);
    stg2(pB0 + ko1 + 32, pB1 + ko1 + 32, lB + q + 8192 + sdA);
    SCB; BARR; LGKM0; SCB;
    PR1; cl16<4>(acc, ag, bf); PR0;
    SCB; BARR; SCB;

    // ---- P3: quadrant (Mh1, ks1) — 8 reads, stage A0(t+2)
    rd4(ag, A1 + laneA + 2048);
    rd4(bf, B1 + laneB);
    stg2(pA0 + ko2, pA1 + ko2, lA + p + sdA);
    SCB; BARR; LGKM0; SCB;
    PR1; cl16<4>(acc, ag, bf); PR0;
    SCB; BARR; SCB;

    // ---- P4: quadrant (Mh0, ks1) — 4 reads (bf reused), stage B0(t+2), vmcnt(4)
    rd4(af, A1 + laneA);
    stg2(pB0 + ko2, pB1 + ko2, lB + p + sdA);
    SCB; BARR; LGKM0; SCB;
    PR1; cl16<0>(acc, af, bf); PR0;
    VMW(4);
    SCB; BARR; SCB;
  }

  VMW(0);
  __syncthreads();

  // ---- epilogue: per-row (max, sumexp) over this 256-col block ----
  float bv[4];
  #pragma unroll
  for (int u = 0; u < 4; ++u) bv[u] = bias[cb * 256 + wc * 64 + u * 16 + lr];
  float* lm = (float*)lds;                 // [4][256]
  float* lsm = lm + 1024;                  // [4][256]
  #pragma unroll
  for (int mi = 0; mi < 8; ++mi) {
    #pragma unroll
    for (int j = 0; j < 4; ++j) {
      float v0 = acc[mi][0][j] + bv[0], v1 = acc[mi][1][j] + bv[1];
      float v2 = acc[mi][2][j] + bv[2], v3 = acc[mi][3][j] + bv[3];
      float m = fmaxf(fmaxf(v0, v1), fmaxf(v2, v3));
      #pragma unroll
      for (int d = 1; d < 16; d <<= 1) m = fmaxf(m, __shfl_xor(m, d));
      float s = __expf(v0 - m) + __expf(v1 - m) + __expf(v2 - m) + __expf(v3 - m);
      #pragma unroll
      for (int d = 1; d < 16; d <<= 1) s += __shfl_xor(s, d);
      if (lr == 0) {
        int row = wr * 128 + mi * 16 + (lane >> 4) * 4 + j;
        lm[wc * 256 + row] = m; lsm[wc * 256 + row] = s;
      }
    }
  }
  __syncthreads();
  if (tid < 256) {
    float m0 = lm[tid], m1 = lm[256 + tid], m2 = lm[512 + tid], m3 = lm[768 + tid];
    float M = fmaxf(fmaxf(m0, m1), fmaxf(m2, m3));
    float S = lsm[tid] * __expf(m0 - M) + lsm[256 + tid] * __expf(m1 - M)
            + lsm[512 + tid] * __expf(m2 - M) + lsm[768 + tid] * __expf(m3 - M);
    int gr = rb * 256 + tid;
    pm[(size_t)gr * pstride + cb] = M;
    ps[(size_t)gr * pstride + cb] = S;
  }
}

// ---------------- finish: target logits + LSE reduce + NLL ----------------
DEVI float lsew(const float* m, const float* s, int nb, int lane) {
  float M = -3e38f;
  for (int i = lane; i < nb; i += 64) M = fmaxf(M, m[i]);
  #pragma unroll
  for (int d = 1; d < 64; d <<= 1) M = fmaxf(M, __shfl_xor(M, d));
  float S = 0.f;
  for (int i = lane; i < nb; i += 64) S += s[i] * __expf(m[i] - M);
  #pragma unroll
  for (int d = 1; d < 64; d <<= 1) S += __shfl_xor(S, d);
  return M + __logf(S);
}

__global__ void finish_kernel(const _Float16* __restrict__ ph0, const _Float16* __restrict__ headw,
                              const float* __restrict__ headb,
                              const _Float16* __restrict__ ph1c, const _Float16* __restrict__ w1p,
                              const float* __restrict__ b1p,
                              const _Float16* __restrict__ ph2c, const _Float16* __restrict__ w2p,
                              const float* __restrict__ b2p,
                              const int* __restrict__ headcol, const int* __restrict__ tailpos,
                              const int* __restrict__ pos1, const int* __restrict__ pos2,
                              const int* __restrict__ cl,
                              const float* __restrict__ pmh, const float* __restrict__ psh,
                              const float* __restrict__ pm1, const float* __restrict__ ps1,
                              const float* __restrict__ pm2, const float* __restrict__ ps2,
                              float* __restrict__ out)
{
  int n = blockIdx.x;
  int tid = threadIdx.x, lane = tid & 63, wid = tid >> 6;
  __shared__ float sh[6];
  int c = cl[n];
  if (wid == 0) {
    int hc = headcol[n];
    const f16x8* a = (const f16x8*)(ph0 + (size_t)n * 1024 + lane * 16);
    const f16x8* ww = (const f16x8*)(headw + (size_t)hc * 1024 + lane * 16);
    float s = 0.f;
    #pragma unroll
    for (int u = 0; u < 2; u++) {
      f16x8 av = a[u], wv = ww[u];
      #pragma unroll
      for (int j = 0; j < 8; j++) s += (float)av[j] * (float)wv[j];
    }
    #pragma unroll
    for (int d = 1; d < 64; d <<= 1) s += __shfl_xor(s, d);
    if (lane == 0) sh[0] = s + headb[hc];
  } else if (wid == 1 && c == 1) {
    int p = pos1[n], t = tailpos[n];
    f16x4 av = *(const f16x4*)(ph1c + (size_t)p * 256 + lane * 4);
    f16x4 wv = *(const f16x4*)(w1p + (size_t)t * 256 + lane * 4);
    float s = (float)av[0] * (float)wv[0] + (float)av[1] * (float)wv[1]
            + (float)av[2] * (float)wv[2] + (float)av[3] * (float)wv[3];
    #pragma unroll
    for (int d = 1; d < 64; d <<= 1) s += __shfl_xor(s, d);
    float l = lsew(pm1 + (size_t)p * PSTT, ps1 + (size_t)p * PSTT, NCBT, lane);
    if (lane == 0) { sh[1] = s + b1p[t]; sh[4] = l; }
  } else if (wid == 2 && c == 2) {
    int p = pos2[n], t = tailpos[n];
    const _Float16* a = ph2c + (size_t)p * 128 + lane * 2;
    const _Float16* ww = w2p + (size_t)t * 128 + lane * 2;
    float s = (float)a[0] * (float)ww[0] + (float)a[1] * (float)ww[1];
    #pragma unroll
    for (int d = 1; d < 64; d <<= 1) s += __shfl_xor(s, d);
    float l = lsew(pm2 + (size_t)p * PSTT, ps2 + (size_t)p * PSTT, NCBT, lane);
    if (lane == 0) { sh[2] = s + b2p[t]; sh[5] = l; }
  } else if (wid == 3) {
    float l = lsew(pmh + (size_t)n * PSTH, psh + (size_t)n * PSTH, NCBH, lane);
    if (lane == 0) sh[3] = l;
  }
  __syncthreads();
  if (tid == 0) {
    float nll = sh[3] - sh[0];
    if (c == 1)      nll += sh[4] - sh[1];
    else if (c == 2) nll += sh[5] - sh[2];
    out[n] = nll;
  }
}

// ---------------- driver ----------------
extern "C" void kernel_launch(void* const* d_in, const int* in_sizes, int n_in,
                              void* d_out, int out_size, void* d_ws, size_t ws_size,
                              hipStream_t stream)
{
  const int*   x         = (const int*)d_in[0];
  const int*   labels    = (const int*)d_in[1];
  const float* emb_w0    = (const float*)d_in[2];
  const float* emb_w1    = (const float*)d_in[3];
  const float* emb_w2    = (const float*)d_in[4];
  const float* emb_proj0 = (const float*)d_in[5];
  const float* emb_proj1 = (const float*)d_in[6];
  const float* emb_proj2 = (const float*)d_in[7];
  const float* out_w0    = (const float*)d_in[8];
  const float* out_b0    = (const float*)d_in[9];
  const float* out_w1    = (const float*)d_in[10];
  const float* out_b1    = (const float*)d_in[11];
  const float* out_w2    = (const float*)d_in[12];
  const float* out_b2    = (const float*)d_in[13];
  const float* out_proj0 = (const float*)d_in[14];
  const float* out_proj1 = (const float*)d_in[15];
  const float* out_proj2 = (const float*)d_in[16];
  const float* cluster_w = (const float*)d_in[17];
  const float* cluster_b = (const float*)d_in[18];
  float* out = (float*)d_out;

  char* ws = (char*)d_ws;
  size_t off = 0;
  auto alloc = [&](size_t bytes) -> void* {
    void* p = ws + off;
    off = (off + bytes + 255) & ~(size_t)255;
    return p;
  };
  _Float16* headw = (_Float16*)alloc((size_t)HEADP * 1024 * 2);
  float*    headb = (float*)alloc((size_t)HEADP * 4);
  _Float16* w1p   = (_Float16*)alloc((size_t)VTP * 256 * 2);
  float*    b1p   = (float*)alloc((size_t)VTP * 4);
  _Float16* w2p   = (_Float16*)alloc((size_t)VTP * 128 * 2);
  float*    b2p   = (float*)alloc((size_t)VTP * 4);
  _Float16* ep0f  = (_Float16*)alloc((size_t)1024 * 1024 * 2);
  _Float16* ep1f  = (_Float16*)alloc((size_t)1024 * 256 * 2);
  _Float16* ep2f  = (_Float16*)alloc((size_t)1024 * 64 * 2);
  _Float16* op0T  = (_Float16*)alloc((size_t)1024 * 1024 * 2);
  _Float16* op1T  = (_Float16*)alloc((size_t)256 * 1024 * 2);
  _Float16* op2T  = (_Float16*)alloc((size_t)128 * 1024 * 2);
  _Float16* E0    = (_Float16*)alloc((size_t)NROWS * 1024 * 2);
  _Float16* E1    = (_Float16*)alloc((size_t)NROWS * 256 * 2);
  _Float16* E2    = (_Float16*)alloc((size_t)NROWS * 64 * 2);
  _Float16* hid   = (_Float16*)alloc((size_t)NROWS * 1024 * 2);
  _Float16* ph0   = (_Float16*)alloc((size_t)NROWS * 1024 * 2);
  _Float16* ph1c  = (_Float16*)alloc((size_t)NROWS * 256 * 2);
  _Float16* ph2c  = (_Float16*)alloc((size_t)NROWS * 128 * 2);
  float* pmh = (float*)alloc((size_t)NROWS * PSTH * 4);
  float* psh = (float*)alloc((size_t)NROWS * PSTH * 4);
  float* pm1 = (float*)alloc((size_t)NROWS * PSTT * 4);
  float* ps1 = (float*)alloc((size_t)NROWS * PSTT * 4);
  float* pm2 = (float*)alloc((size_t)NROWS * PSTT * 4);
  float* ps2 = (float*)alloc((size_t)NROWS * PSTT * 4);
  int* L1 = (int*)alloc(NROWS * 4);
  int* L2 = (int*)alloc(NROWS * 4);
  int* T0 = (int*)alloc(NROWS * 4);
  int* T1 = (int*)alloc(NROWS * 4);
  int* T2 = (int*)alloc(NROWS * 4);
  int* counts  = (int*)alloc(16 * 4);
  int* cl      = (int*)alloc(NROWS * 4);
  int* headcol = (int*)alloc(NROWS * 4);
  int* tailpos = (int*)alloc(NROWS * 4);
  int* pos1    = (int*)alloc(NROWS * 4);
  int* pos2    = (int*)alloc(NROWS * 4);
  (void)ws_size; (void)in_sizes; (void)n_in; (void)out_size;

  prep_kernel<<<1, 256, 0, stream>>>(x, labels, cl, headcol, tailpos, pos1, pos2,
                                     L1, L2, T0, T1, T2, counts);

  fused_pack<<<PB8, 256, 0, stream>>>(out_w0, out_b0, cluster_w, cluster_b,
                                      out_w1, out_b1, out_w2, out_b2,
                                      emb_proj0, emb_proj1, emb_proj2,
                                      out_proj0, out_proj1, out_proj2,
                                      headw, headb, w1p, b1p, w2p, b2p,
                                      ep0f, ep1f, ep2f, op0T, op1T, op2T);

  fused_gather<<<2688, 256, 0, stream>>>(emb_w0, emb_w1, emb_w2, x, T0, T1, T2, E0, E1, E2);

  // hidden per token cluster (scatter via T-lists)
  gemm128<<<dim3(16, 8), 256, 0, stream>>>(E0, 1024, ep0f, 1024, hid, 1024, 1024,
                                           nullptr, T0, counts + 2, 1024);
  gemm128<<<dim3(16, 8), 256, 0, stream>>>(E1, 256, ep1f, 256, hid, 1024, 1024,
                                           nullptr, T1, counts + 3, 256);
  gemm128<<<dim3(16, 8), 256, 0, stream>>>(E2, 64, ep2f, 64, hid, 1024, 1024,
                                           nullptr, T2, counts + 4, 64);

  // projections
  gemm128<<<dim3(16, 8), 256, 0, stream>>>(hid, 1024, op0T, 1024, ph0, 1024, 1024,
                                           nullptr, nullptr, nullptr, 1024);
  gemm128<<<dim3(16, 2), 256, 0, stream>>>(hid, 1024, op1T, 1024, ph1c, 256, 256,
                                           L1, nullptr, counts + 0, 1024);
  gemm128<<<dim3(16, 1), 256, 0, stream>>>(hid, 1024, op2T, 1024, ph2c, 128, 128,
                                           L2, nullptr, counts + 1, 1024);

  // logits + online-LSE partials (256-tile quadrant-phase)
  gemm_lse<<<8 * NCBH, 512, 0, stream>>>(ph0, 1024, headw, 1024, headb, nullptr,
                                         pmh, psh, PSTH, 1024, 8);
  gemm_lse<<<8 * NCBT, 512, 0, stream>>>(ph1c, 256, w1p, 256, b1p, counts + 0,
                                         pm1, ps1, PSTT, 256, 8);
  gemm_lse<<<8 * NCBT, 512, 0, stream>>>(ph2c, 128, w2p, 128, b2p, counts + 1,
                                         pm2, ps2, PSTT, 128, 8);

  finish_kernel<<<NROWS, 256, 0, stream>>>(ph0, headw, headb, ph1c, w1p, b1p,
                                           ph2c, w2p, b2p, headcol, tailpos, pos1, pos2, cl,
                                           pmh, psh, pm1, ps1, pm2, ps2, out);
}

// Round 4
// 368.074 us; speedup vs baseline: 1.1434x; 1.1434x over previous
//
#include <hip/hip_runtime.h>

typedef _Float16 f16x8 __attribute__((ext_vector_type(8)));
typedef _Float16 f16x4 __attribute__((ext_vector_type(4)));
typedef float f32x4 __attribute__((ext_vector_type(4)));
typedef unsigned char u8;

#define DEVI __device__ __forceinline__

constexpr int NROWS = 2048;
constexpr int HEADV = 20002;
constexpr int HEADP = 20480;   // 64*320
constexpr int NCBH  = 64;
constexpr int PSTH  = 64;
constexpr int VT    = 40000;
constexpr int VTP   = 40320;   // 126*320
constexpr int NCBT  = 126;
constexpr int PSTT  = 128;

DEVI void glds16(const void* g, void* l) {
  __builtin_amdgcn_global_load_lds((const __attribute__((address_space(1))) unsigned int*)g,
                                   (__attribute__((address_space(3))) unsigned int*)l,
                                   16, 0, 0);
}

#define VMW(N) asm volatile("s_waitcnt vmcnt(" #N ")" ::: "memory")
#define SCB    __builtin_amdgcn_sched_barrier(0)
#define BARR   __builtin_amdgcn_s_barrier()
#define PR1 __builtin_amdgcn_s_setprio(1)
#define PR0 __builtin_amdgcn_s_setprio(0)

// ---------------- fp8 e4m3fn converters (hand-rolled, RNE) ----------------
DEVI unsigned int to_e4m3(float f) {
  unsigned u = __float_as_uint(f);
  unsigned s = (u >> 24) & 0x80u;
  float a = fabsf(f);
  if (!(a < 448.f)) return s | 0x7E;
  if (a < 0.00097656f) return s;
  int exp = (int)((u >> 23) & 0xFF) - 127;
  int qexp = exp < -6 ? -6 : exp;
  int n = __float2int_rn(a * exp2f((float)(3 - qexp)));
  if (n >= 16) { qexp++; n = 8; }
  return s | (unsigned)(n < 8 ? n : (((qexp + 7) << 3) | (n - 8)));
}

DEVI float fr8(unsigned b) {
  unsigned e = (b >> 3) & 15u, m = b & 7u;
  float v;
  if (e) v = __uint_as_float(((e + 120u) << 23) | (m << 20));
  else   v = (float)m * 0.001953125f;
  return (b & 0x80u) ? -v : v;
}

// ---------------- prep: per-row label info + compaction lists ----------------
__global__ void prep_kernel(const int* __restrict__ x, const int* __restrict__ labels,
                            int* cl, int* headcol, int* tailpos, int* pos1, int* pos2,
                            int* L1, int* L2, int* T0, int* T1, int* T2, int* counts)
{
  __shared__ int sc[3][256];
  int tid = threadIdx.x;
  int base = tid * 8;
  int lcl[8]; int c1 = 0, c2 = 0;
  for (int j = 0; j < 8; j++) {
    int l = labels[base + j];
    int c = l < 20000 ? 0 : (l < 60000 ? 1 : 2);
    lcl[j] = c;
    cl[base + j] = c;
    headcol[base + j] = c == 0 ? l : (c == 1 ? 20001 : 20000);
    tailpos[base + j] = c == 1 ? l - 20000 : (c == 2 ? l - 60000 : 0);
    if (c == 1) c1++; else if (c == 2) c2++;
  }
  sc[1][tid] = c1; sc[2][tid] = c2;
  __syncthreads();
  for (int d = 1; d < 256; d <<= 1) {
    int v1 = tid >= d ? sc[1][tid - d] : 0;
    int v2 = tid >= d ? sc[2][tid - d] : 0;
    __syncthreads();
    sc[1][tid] += v1; sc[2][tid] += v2;
    __syncthreads();
  }
  int o1 = sc[1][tid] - c1, o2 = sc[2][tid] - c2;
  int cnt1 = sc[1][255], cnt2 = sc[2][255];
  for (int j = 0; j < 8; j++) {
    int n = base + j; int c = lcl[j];
    if (c == 1)      { pos1[n] = o1; L1[o1] = n; o1++; pos2[n] = 0; }
    else if (c == 2) { pos2[n] = o2; L2[o2] = n; o2++; pos1[n] = 0; }
    else             { pos1[n] = 0; pos2[n] = 0; }
  }
  for (int i = cnt1 + tid; i < NROWS; i += 256) L1[i] = 0;
  for (int i = cnt2 + tid; i < NROWS; i += 256) L2[i] = 0;
  if (tid == 0) { counts[0] = cnt1; counts[1] = cnt2; }
  __syncthreads();
  int tcl[8]; int t0 = 0, t1 = 0, t2 = 0;
  for (int j = 0; j < 8; j++) {
    int t = x[base + j];
    int c = t < 20000 ? 0 : (t < 60000 ? 1 : 2);
    tcl[j] = c;
    if (c == 0) t0++; else if (c == 1) t1++; else t2++;
  }
  sc[0][tid] = t0; sc[1][tid] = t1; sc[2][tid] = t2;
  __syncthreads();
  for (int d = 1; d < 256; d <<= 1) {
    int v0 = tid >= d ? sc[0][tid - d] : 0;
    int v1 = tid >= d ? sc[1][tid - d] : 0;
    int v2 = tid >= d ? sc[2][tid - d] : 0;
    __syncthreads();
    sc[0][tid] += v0; sc[1][tid] += v1; sc[2][tid] += v2;
    __syncthreads();
  }
  int q0 = sc[0][tid] - t0, q1 = sc[1][tid] - t1, q2 = sc[2][tid] - t2;
  int tc0 = sc[0][255], tc1 = sc[1][255], tc2 = sc[2][255];
  for (int j = 0; j < 8; j++) {
    int n = base + j; int c = tcl[j];
    if (c == 0) T0[q0++] = n;
    else if (c == 1) T1[q1++] = n;
    else T2[q2++] = n;
  }
  for (int i = tc0 + tid; i < NROWS; i += 256) T0[i] = 0;
  for (int i = tc1 + tid; i < NROWS; i += 256) T1[i] = 0;
  for (int i = tc2 + tid; i < NROWS; i += 256) T2[i] = 0;
  if (tid == 0) { counts[2] = tc0; counts[3] = tc1; counts[4] = tc2; }
}

// ---------------- fused pack / convert / transpose ----------------
// fp8 W packs (x64), f32 biases, f16 projections
constexpr int PB_A = HEADP * 1024 / 8 / 256;          // 10240  headw fp8
constexpr int PB_B = PB_A + VTP * 256 / 8 / 256;      // +5040  w1q
constexpr int PB_C = PB_B + VTP * 128 / 8 / 256;      // +2520  w2q
constexpr int PB_D = PB_C + 1024;                     // ep0f
constexpr int PB_E = PB_D + 256;                      // ep1f
constexpr int PB_F = PB_E + 64;                       // ep2f
constexpr int PB_G = PB_F + 1024;                     // op0T
constexpr int PB_H = PB_G + 256;                      // op1T
constexpr int PB_I = PB_H + 128;                      // op2T

DEVI void cvt_f16(const float* src, _Float16* dst, int vb, int tid) {
  int g = vb * 256 + tid;
  float4 v = *(const float4*)(src + (size_t)g * 4);
  f16x4 o = {(_Float16)v.x, (_Float16)v.y, (_Float16)v.z, (_Float16)v.w};
  *(f16x4*)(dst + (size_t)g * 4) = o;
}

DEVI void tr32(const float* in, _Float16* out, int C, int bx, int by, int tid) {
  __shared__ float tile[32][33];
  int c0 = bx * 32, r0 = by * 32;
  int tx = tid & 31, ty = tid >> 5;
  for (int i = 0; i < 4; i++) {
    int c = c0 + tx; int r = r0 + ty + i * 8;
    tile[ty + i * 8][tx] = (c < C) ? in[(size_t)r * C + c] : 0.f;
  }
  __syncthreads();
  for (int i = 0; i < 4; i++)
    out[(size_t)(c0 + ty + i * 8) * 1024 + r0 + tx] = (_Float16)tile[tx][ty + i * 8];
}

DEVI unsigned long pack8(const float* v) {
  unsigned long p = 0;
  #pragma unroll
  for (int j = 0; j < 8; j++) p |= (unsigned long)to_e4m3(v[j] * 64.f) << (8 * j);
  return p;
}

__global__ void fused_pack(const float* __restrict__ out_w0, const float* __restrict__ out_b0,
                           const float* __restrict__ cluster_w, const float* __restrict__ cluster_b,
                           const float* __restrict__ out_w1, const float* __restrict__ out_b1,
                           const float* __restrict__ out_w2, const float* __restrict__ out_b2,
                           const float* __restrict__ emb_proj0, const float* __restrict__ emb_proj1,
                           const float* __restrict__ emb_proj2,
                           const float* __restrict__ out_proj0, const float* __restrict__ out_proj1,
                           const float* __restrict__ out_proj2,
                           u8* headw, float* headb,
                           u8* w1q, float* b1p, u8* w2q, float* b2p,
                           _Float16* ep0f, _Float16* ep1f, _Float16* ep2f,
                           _Float16* op0T, _Float16* op1T, _Float16* op2T)
{
  int bid = blockIdx.x, tid = threadIdx.x;
  if (bid < PB_A) {
    int g = bid * 256 + tid;
    int r = g >> 7, c8 = (g & 127) * 8;
    float v[8] = {};
    if (r < 20000) {
      *(float4*)v = *(const float4*)(out_w0 + (size_t)r * 1024 + c8);
      *(float4*)(v + 4) = *(const float4*)(out_w0 + (size_t)r * 1024 + c8 + 4);
    } else if (r < 20002) {
      *(float4*)v = *(const float4*)(cluster_w + (size_t)(r - 20000) * 1024 + c8);
      *(float4*)(v + 4) = *(const float4*)(cluster_w + (size_t)(r - 20000) * 1024 + c8 + 4);
    }
    *(unsigned long*)(headw + (size_t)r * 1024 + c8) = pack8(v);
    if (g < HEADP) headb[g] = g < 20000 ? out_b0[g] : (g < HEADV ? cluster_b[g - 20000] : -1e30f);
  } else if (bid < PB_B) {
    int g = (bid - PB_A) * 256 + tid;
    int r = g >> 5, c8 = (g & 31) * 8;
    float v[8] = {};
    if (r < VT) {
      *(float4*)v = *(const float4*)(out_w1 + (size_t)r * 256 + c8);
      *(float4*)(v + 4) = *(const float4*)(out_w1 + (size_t)r * 256 + c8 + 4);
    }
    *(unsigned long*)(w1q + (size_t)r * 256 + c8) = pack8(v);
    if (g < VTP) b1p[g] = g < VT ? out_b1[g] : -1e30f;
  } else if (bid < PB_C) {
    int g = (bid - PB_B) * 256 + tid;
    int r = g >> 4, c8 = (g & 15) * 8;
    float v[8] = {};
    if (r < VT && c8 < 64) {
      *(float4*)v = *(const float4*)(out_w2 + (size_t)r * 64 + c8);
      *(float4*)(v + 4) = *(const float4*)(out_w2 + (size_t)r * 64 + c8 + 4);
    }
    *(unsigned long*)(w2q + (size_t)r * 128 + c8) = pack8(v);
    if (g < VTP) b2p[g] = g < VT ? out_b2[g] : -1e30f;
  } else if (bid < PB_D) { cvt_f16(emb_proj0, ep0f, bid - PB_C, tid); }
  else if (bid < PB_E) { cvt_f16(emb_proj1, ep1f, bid - PB_D, tid); }
  else if (bid < PB_F) { cvt_f16(emb_proj2, ep2f, bid - PB_E, tid); }
  else if (bid < PB_G) { int l = bid - PB_F; tr32(out_proj0, op0T, 1024, l & 31, l >> 5, tid); }
  else if (bid < PB_H) { int l = bid - PB_G; tr32(out_proj1, op1T, 256, l & 7, l >> 3, tid); }
  else                 { int l = bid - PB_H; tr32(out_proj2, op2T, 64, l & 3, l >> 2, tid); }
}

// ---------------- fused gather ----------------
DEVI void gat(const float* emb, const int* x, const int* list, _Float16* dst,
              int tbase, int vmax, int log2E, int vb, int tid) {
  int g = vb * 256 + tid;
  int r = g >> (log2E - 2);
  int e4 = (g & ((1 << (log2E - 2)) - 1)) << 2;
  int n = list[r];
  int tl = x[n] - tbase;
  tl = tl < 0 ? 0 : (tl >= vmax ? vmax - 1 : tl);
  float4 v = *(const float4*)(emb + ((size_t)tl << log2E) + e4);
  f16x4 o = {(_Float16)(v.x * 32.f), (_Float16)(v.y * 32.f),
             (_Float16)(v.z * 32.f), (_Float16)(v.w * 32.f)};
  *(f16x4*)(dst + ((size_t)r << log2E) + e4) = o;
}

__global__ void fused_gather(const float* __restrict__ emb_w0, const float* __restrict__ emb_w1,
                             const float* __restrict__ emb_w2, const int* __restrict__ x,
                             const int* __restrict__ T0, const int* __restrict__ T1,
                             const int* __restrict__ T2,
                             _Float16* E0, _Float16* E1, _Float16* E2)
{
  int bid = blockIdx.x, tid = threadIdx.x;
  if (bid < 2048)      gat(emb_w0, x, T0, E0, 0, 20000, 10, bid, tid);
  else if (bid < 2560) gat(emb_w1, x, T1, E1, 20000, 40000, 8, bid - 2048, tid);
  else                 gat(emb_w2, x, T2, E2, 60000, 40000, 6, bid - 2560, tid);
}

// ---------------- 128-tile f16 GEMM (hidden / projection stages) ----------------
// optional dual-write: f16 C plus fp8 Cq = e4m3(8*val)
__global__ __launch_bounds__(256)
void gemm128(const _Float16* __restrict__ A, int lda,
             const _Float16* __restrict__ Wm, int ldw,
             _Float16* __restrict__ C, int ldc, int Nvalid,
             u8* __restrict__ Cq, int ldq,
             const int* __restrict__ amap, const int* __restrict__ cmap,
             const int* __restrict__ cnt, int K)
{
  int rb = blockIdx.x, cb = blockIdx.y;
  int valid = cnt ? *cnt : NROWS;
  if (cnt && rb * 128 >= valid) return;
  __shared__ __attribute__((aligned(16))) _Float16 As[128 * 32];
  __shared__ __attribute__((aligned(16))) _Float16 Ws[128 * 32];
  int tid = threadIdx.x;
  int lane = tid & 63, wid = tid >> 6;
  int wr = wid >> 1, wc = wid & 1;
  int sr = wid * 32 + (lane >> 2);
  int arow0 = rb * 128 + sr, arow1 = arow0 + 16;
  if (amap) { arow0 = amap[arow0]; arow1 = amap[arow1]; }
  int ko = (lane & 3) * 8;
  const _Float16* ag0 = A + (size_t)arow0 * lda + ko;
  const _Float16* ag1 = A + (size_t)arow1 * lda + ko;
  const _Float16* wg0 = Wm + (size_t)(cb * 128 + sr) * ldw + ko;
  const _Float16* wg1 = wg0 + (size_t)16 * ldw;
  _Float16* as0 = As + (wid * 32) * 32;
  _Float16* as1 = as0 + 16 * 32;
  _Float16* ws0 = Ws + (wid * 32) * 32;
  _Float16* ws1 = ws0 + 16 * 32;
  f32x4 acc[4][4] = {};
  int lr = lane & 15, lk = (lane >> 4) * 8;
  const int nk = K >> 5;
  for (int kt = 0; kt < nk; ++kt) {
    int kofs = kt * 32;
    glds16(ag0 + kofs, as0);
    glds16(ag1 + kofs, as1);
    glds16(wg0 + kofs, ws0);
    glds16(wg1 + kofs, ws1);
    __syncthreads();
    f16x8 af[4], bf[4];
    #pragma unroll
    for (int mi = 0; mi < 4; mi++)
      af[mi] = *(const f16x8*)(As + (wr * 64 + mi * 16 + lr) * 32 + lk);
    #pragma unroll
    for (int ni = 0; ni < 4; ni++)
      bf[ni] = *(const f16x8*)(Ws + (wc * 64 + ni * 16 + lr) * 32 + lk);
    #pragma unroll
    for (int mi = 0; mi < 4; mi++)
      #pragma unroll
      for (int ni = 0; ni < 4; ni++)
        acc[mi][ni] = __builtin_amdgcn_mfma_f32_16x16x32_f16(af[mi], bf[ni], acc[mi][ni], 0, 0, 0);
    __syncthreads();
  }
  #pragma unroll
  for (int mi = 0; mi < 4; mi++) {
    #pragma unroll
    for (int j = 0; j < 4; j++) {
      int rl = wr * 64 + mi * 16 + (lane >> 4) * 4 + j;
      int rg = rb * 128 + rl;
      if (rg >= valid) continue;
      int orow = cmap ? cmap[rg] : rg;
      #pragma unroll
      for (int ni = 0; ni < 4; ni++) {
        int col = cb * 128 + wc * 64 + ni * 16 + (lane & 15);
        if (col < Nvalid) {
          float v = acc[mi][ni][j];
          C[(size_t)orow * ldc + col] = (_Float16)v;
          if (Cq) Cq[(size_t)orow * ldq + col] = (u8)to_e4m3(v * 8.f);
        }
      }
    }
  }
}

// ---------------- fp8 256x320 GEMM + online-LSE, 3-region pipeline ----------------
__global__ __launch_bounds__(512, 2)
void gemm_lse8(const u8* __restrict__ Aq, const u8* __restrict__ Wq,
               const float* __restrict__ bias, const int* __restrict__ cnt,
               float* __restrict__ pm, float* __restrict__ ps,
               int pstride, int K, int nrb)
{
  constexpr int RSZ = 36864;                 // 16 KB A + 20 KB B per slice
  __shared__ __attribute__((aligned(16))) u8 lds[3 * RSZ];

  int bid = blockIdx.x;
  int q = gridDim.x >> 3;                    // grid % 8 == 0
  int w = (bid & 7) * q + (bid >> 3);        // XCD-contiguous
  int rb = w % nrb, cb = w / nrb;
  int valid = cnt ? *cnt : NROWS;
  if (rb * 256 >= valid) return;

  int tid = threadIdx.x;
  int lane = tid & 63, wid = tid >> 6;
  int wm = wid >> 2, wn = wid & 3;
  int lr = lane & 15, g = lane >> 4;

  // staging: chunk c -> row c>>2, phys col16 c&3 holds logical col16 (c&3)^f(row)
  auto soff = [K](int c) -> size_t {
    int r = c >> 2;
    int L = (c & 3) ^ (((r >> 1) & 3) ^ (((r >> 3) & 1) << 1));
    return (size_t)r * K + L * 16;
  };
  const u8* aB = Aq + (size_t)(rb * 256) * K;
  const u8* wB = Wq + (size_t)(cb * 320) * K;
  const u8* aS0 = aB + soff(tid);
  const u8* aS1 = aB + soff(tid + 512);
  const u8* bS0 = wB + soff(tid);
  const u8* bS1 = wB + soff(tid + 512);
  const u8* bS2 = wB + soff(1024 + tid);
  int dA0 = tid * 16, dA1 = (tid + 512) * 16;
  int dB0 = 16384 + tid * 16, dB1 = 16384 + (tid + 512) * 16, dB2 = 16384 + (1024 + tid) * 16;

  // fragment read offsets (lane-constant swizzle)
  int fs = ((lr >> 1) & 3) ^ (((lr >> 3) & 1) << 1);
  int aoff0 = (wm * 128 + lr) * 64 + ((((g >> 1)) ^ fs) << 4) + (g & 1) * 8;
  int aoff1 = (wm * 128 + lr) * 64 + (((2 + (g >> 1)) ^ fs) << 4) + (g & 1) * 8;
  int boff0 = (wn * 80 + lr) * 64 + ((((g >> 1)) ^ fs) << 4) + (g & 1) * 8;
  int boff1 = (wn * 80 + lr) * 64 + (((2 + (g >> 1)) ^ fs) << 4) + (g & 1) * 8;

  u8 *r0 = lds, *r1 = lds + RSZ, *r2 = lds + 2 * RSZ;
  auto STAGE = [&](u8* rg, int k0) {
    glds16(aS0 + k0, rg + dA0);
    glds16(aS1 + k0, rg + dA1);
    glds16(bS0 + k0, rg + dB0);
    glds16(bS1 + k0, rg + dB1);
    if (wid < 4) glds16(bS2 + k0, rg + dB2);
  };

  f32x4 acc[8][5] = {};
  const int nk = K >> 6;                     // nk >= 2

  STAGE(r0, 0);
  STAGE(r1, 64);
  VMW(4); SCB; BARR; SCB;

  for (int t = 0; t < nk; ++t) {
    int ts = t + 2; if (ts > nk - 1) ts = nk - 1;
    STAGE(r2, ts * 64);
    const u8* rB_ = r0 + 16384;
    PR1;
    #pragma unroll
    for (int kk = 0; kk < 2; ++kk) {
      int ao = kk ? aoff1 : aoff0, bo = kk ? boff1 : boff0;
      long bq[5];
      #pragma unroll
      for (int ni = 0; ni < 5; ++ni) bq[ni] = *(const long*)(rB_ + bo + ni * 1024);
      #pragma unroll
      for (int mi = 0; mi < 8; ++mi) {
        long av = *(const long*)(r0 + ao + mi * 1024);
        #pragma unroll
        for (int ni = 0; ni < 5; ++ni)
          acc[mi][ni] = __builtin_amdgcn_mfma_f32_16x16x32_fp8_fp8(av, bq[ni], acc[mi][ni], 0, 0, 0);
      }
    }
    PR0;
    VMW(4); SCB; BARR; SCB;
    u8* tmp = r0; r0 = r1; r1 = r2; r2 = tmp;
  }
  VMW(0); SCB; BARR; SCB;

  // ---- epilogue: unscale 1/512 + bias, per-row (max,sumexp) over 320 cols ----
  float* lm = (float*)lds;                   // [4][256]
  float* lsm = lm + 1024;
  float bv[5];
  #pragma unroll
  for (int ni = 0; ni < 5; ++ni) bv[ni] = bias[cb * 320 + wn * 80 + ni * 16 + lr];
  constexpr float INV = 1.f / 512.f;
  #pragma unroll
  for (int mi = 0; mi < 8; ++mi) {
    #pragma unroll
    for (int j = 0; j < 4; ++j) {
      float v0 = acc[mi][0][j] * INV + bv[0];
      float v1 = acc[mi][1][j] * INV + bv[1];
      float v2 = acc[mi][2][j] * INV + bv[2];
      float v3 = acc[mi][3][j] * INV + bv[3];
      float v4 = acc[mi][4][j] * INV + bv[4];
      float m = fmaxf(fmaxf(fmaxf(v0, v1), fmaxf(v2, v3)), v4);
      #pragma unroll
      for (int d = 1; d < 16; d <<= 1) m = fmaxf(m, __shfl_xor(m, d));
      float s = __expf(v0 - m) + __expf(v1 - m) + __expf(v2 - m) + __expf(v3 - m) + __expf(v4 - m);
      #pragma unroll
      for (int d = 1; d < 16; d <<= 1) s += __shfl_xor(s, d);
      if (lr == 0) {
        int row = wm * 128 + mi * 16 + g * 4 + j;
        lm[wn * 256 + row] = m; lsm[wn * 256 + row] = s;
      }
    }
  }
  __syncthreads();
  if (tid < 256) {
    float m0 = lm[tid], m1 = lm[256 + tid], m2 = lm[512 + tid], m3 = lm[768 + tid];
    float M = fmaxf(fmaxf(m0, m1), fmaxf(m2, m3));
    float S = lsm[tid] * __expf(m0 - M) + lsm[256 + tid] * __expf(m1 - M)
            + lsm[512 + tid] * __expf(m2 - M) + lsm[768 + tid] * __expf(m3 - M);
    int gr = rb * 256 + tid;
    pm[(size_t)gr * pstride + cb] = M;
    ps[(size_t)gr * pstride + cb] = S;
  }
}

// ---------------- finish: target logits + LSE reduce + NLL ----------------
DEVI float lsew(const float* m, const float* s, int nb, int lane) {
  float M = -3e38f;
  for (int i = lane; i < nb; i += 64) M = fmaxf(M, m[i]);
  #pragma unroll
  for (int d = 1; d < 64; d <<= 1) M = fmaxf(M, __shfl_xor(M, d));
  float S = 0.f;
  for (int i = lane; i < nb; i += 64) S += s[i] * __expf(m[i] - M);
  #pragma unroll
  for (int d = 1; d < 64; d <<= 1) S += __shfl_xor(S, d);
  return M + __logf(S);
}

__global__ void finish_kernel(const _Float16* __restrict__ ph0, const u8* __restrict__ headw,
                              const float* __restrict__ headb,
                              const _Float16* __restrict__ ph1c, const u8* __restrict__ w1q,
                              const float* __restrict__ b1p,
                              const _Float16* __restrict__ ph2c, const u8* __restrict__ w2q,
                              const float* __restrict__ b2p,
                              const int* __restrict__ headcol, const int* __restrict__ tailpos,
                              const int* __restrict__ pos1, const int* __restrict__ pos2,
                              const int* __restrict__ cl,
                              const float* __restrict__ pmh, const float* __restrict__ psh,
                              const float* __restrict__ pm1, const float* __restrict__ ps1,
                              const float* __restrict__ pm2, const float* __restrict__ ps2,
                              float* __restrict__ out)
{
  int n = blockIdx.x;
  int tid = threadIdx.x, lane = tid & 63, wid = tid >> 6;
  __shared__ float sh[6];
  int c = cl[n];
  constexpr float IW = 1.f / 64.f;
  if (wid == 0) {
    int hc = headcol[n];
    const f16x8* a = (const f16x8*)(ph0 + (size_t)n * 1024 + lane * 16);
    const u8* ww = headw + (size_t)hc * 1024 + lane * 16;
    float s = 0.f;
    #pragma unroll
    for (int u = 0; u < 2; u++) {
      f16x8 av = a[u];
      #pragma unroll
      for (int j = 0; j < 8; j++) s += (float)av[j] * fr8(ww[u * 8 + j]);
    }
    #pragma unroll
    for (int d = 1; d < 64; d <<= 1) s += __shfl_xor(s, d);
    if (lane == 0) sh[0] = s * IW + headb[hc];
  } else if (wid == 1 && c == 1) {
    int p = pos1[n], t = tailpos[n];
    f16x4 av = *(const f16x4*)(ph1c + (size_t)p * 256 + lane * 4);
    const u8* ww = w1q + (size_t)t * 256 + lane * 4;
    float s = (float)av[0] * fr8(ww[0]) + (float)av[1] * fr8(ww[1])
            + (float)av[2] * fr8(ww[2]) + (float)av[3] * fr8(ww[3]);
    #pragma unroll
    for (int d = 1; d < 64; d <<= 1) s += __shfl_xor(s, d);
    float l = lsew(pm1 + (size_t)p * PSTT, ps1 + (size_t)p * PSTT, NCBT, lane);
    if (lane == 0) { sh[1] = s * IW + b1p[t]; sh[4] = l; }
  } else if (wid == 2 && c == 2) {
    int p = pos2[n], t = tailpos[n];
    const _Float16* a = ph2c + (size_t)p * 128 + lane * 2;
    const u8* ww = w2q + (size_t)t * 128 + lane * 2;
    float s = (float)a[0] * fr8(ww[0]) + (float)a[1] * fr8(ww[1]);
    #pragma unroll
    for (int d = 1; d < 64; d <<= 1) s += __shfl_xor(s, d);
    float l = lsew(pm2 + (size_t)p * PSTT, ps2 + (size_t)p * PSTT, NCBT, lane);
    if (lane == 0) { sh[2] = s * IW + b2p[t]; sh[5] = l; }
  } else if (wid == 3) {
    float l = lsew(pmh + (size_t)n * PSTH, psh + (size_t)n * PSTH, NCBH, lane);
    if (lane == 0) sh[3] = l;
  }
  __syncthreads();
  if (tid == 0) {
    float nll = sh[3] - sh[0];
    if (c == 1)      nll += sh[4] - sh[1];
    else if (c == 2) nll += sh[5] - sh[2];
    out[n] = nll;
  }
}

// ---------------- driver ----------------
extern "C" void kernel_launch(void* const* d_in, const int* in_sizes, int n_in,
                              void* d_out, int out_size, void* d_ws, size_t ws_size,
                              hipStream_t stream)
{
  const int*   x         = (const int*)d_in[0];
  const int*   labels    = (const int*)d_in[1];
  const float* emb_w0    = (const float*)d_in[2];
  const float* emb_w1    = (const float*)d_in[3];
  const float* emb_w2    = (const float*)d_in[4];
  const float* emb_proj0 = (const float*)d_in[5];
  const float* emb_proj1 = (const float*)d_in[6];
  const float* emb_proj2 = (const float*)d_in[7];
  const float* out_w0    = (const float*)d_in[8];
  const float* out_b0    = (const float*)d_in[9];
  const float* out_w1    = (const float*)d_in[10];
  const float* out_b1    = (const float*)d_in[11];
  const float* out_w2    = (const float*)d_in[12];
  const float* out_b2    = (const float*)d_in[13];
  const float* out_proj0 = (const float*)d_in[14];
  const float* out_proj1 = (const float*)d_in[15];
  const float* out_proj2 = (const float*)d_in[16];
  const float* cluster_w = (const float*)d_in[17];
  const float* cluster_b = (const float*)d_in[18];
  float* out = (float*)d_out;

  char* ws = (char*)d_ws;
  size_t off = 0;
  auto alloc = [&](size_t bytes) -> void* {
    void* p = ws + off;
    off = (off + bytes + 255) & ~(size_t)255;
    return p;
  };
  u8*    headw = (u8*)alloc((size_t)HEADP * 1024);
  float* headb = (float*)alloc((size_t)HEADP * 4);
  u8*    w1q   = (u8*)alloc((size_t)VTP * 256);
  float* b1p   = (float*)alloc((size_t)VTP * 4);
  u8*    w2q   = (u8*)alloc((size_t)VTP * 128);
  float* b2p   = (float*)alloc((size_t)VTP * 4);
  _Float16* ep0f = (_Float16*)alloc((size_t)1024 * 1024 * 2);
  _Float16* ep1f = (_Float16*)alloc((size_t)1024 * 256 * 2);
  _Float16* ep2f = (_Float16*)alloc((size_t)1024 * 64 * 2);
  _Float16* op0T = (_Float16*)alloc((size_t)1024 * 1024 * 2);
  _Float16* op1T = (_Float16*)alloc((size_t)256 * 1024 * 2);
  _Float16* op2T = (_Float16*)alloc((size_t)128 * 1024 * 2);
  _Float16* E0   = (_Float16*)alloc((size_t)NROWS * 1024 * 2);
  _Float16* E1   = (_Float16*)alloc((size_t)NROWS * 256 * 2);
  _Float16* E2   = (_Float16*)alloc((size_t)NROWS * 64 * 2);
  _Float16* hid  = (_Float16*)alloc((size_t)NROWS * 1024 * 2);
  _Float16* ph0  = (_Float16*)alloc((size_t)NROWS * 1024 * 2);
  u8*       ph0q = (u8*)alloc((size_t)NROWS * 1024);
  _Float16* ph1c = (_Float16*)alloc((size_t)NROWS * 256 * 2);
  u8*       ph1q = (u8*)alloc((size_t)NROWS * 256);
  _Float16* ph2c = (_Float16*)alloc((size_t)NROWS * 128 * 2);
  u8*       ph2q = (u8*)alloc((size_t)NROWS * 128);
  float* pmh = (float*)alloc((size_t)NROWS * PSTH * 4);
  float* psh = (float*)alloc((size_t)NROWS * PSTH * 4);
  float* pm1 = (float*)alloc((size_t)NROWS * PSTT * 4);
  float* ps1 = (float*)alloc((size_t)NROWS * PSTT * 4);
  float* pm2 = (float*)alloc((size_t)NROWS * PSTT * 4);
  float* ps2 = (float*)alloc((size_t)NROWS * PSTT * 4);
  int* L1 = (int*)alloc(NROWS * 4);
  int* L2 = (int*)alloc(NROWS * 4);
  int* T0 = (int*)alloc(NROWS * 4);
  int* T1 = (int*)alloc(NROWS * 4);
  int* T2 = (int*)alloc(NROWS * 4);
  int* counts  = (int*)alloc(16 * 4);
  int* cl      = (int*)alloc(NROWS * 4);
  int* headcol = (int*)alloc(NROWS * 4);
  int* tailpos = (int*)alloc(NROWS * 4);
  int* pos1    = (int*)alloc(NROWS * 4);
  int* pos2    = (int*)alloc(NROWS * 4);
  (void)ws_size; (void)in_sizes; (void)n_in; (void)out_size;

  prep_kernel<<<1, 256, 0, stream>>>(x, labels, cl, headcol, tailpos, pos1, pos2,
                                     L1, L2, T0, T1, T2, counts);

  fused_pack<<<PB_I, 256, 0, stream>>>(out_w0, out_b0, cluster_w, cluster_b,
                                       out_w1, out_b1, out_w2, out_b2,
                                       emb_proj0, emb_proj1, emb_proj2,
                                       out_proj0, out_proj1, out_proj2,
                                       headw, headb, w1q, b1p, w2q, b2p,
                                       ep0f, ep1f, ep2f, op0T, op1T, op2T);

  fused_gather<<<2688, 256, 0, stream>>>(emb_w0, emb_w1, emb_w2, x, T0, T1, T2, E0, E1, E2);

  // hidden per token cluster (scatter via T-lists)
  gemm128<<<dim3(16, 8), 256, 0, stream>>>(E0, 1024, ep0f, 1024, hid, 1024, 1024,
                                           nullptr, 0, nullptr, T0, counts + 2, 1024);
  gemm128<<<dim3(16, 8), 256, 0, stream>>>(E1, 256, ep1f, 256, hid, 1024, 1024,
                                           nullptr, 0, nullptr, T1, counts + 3, 256);
  gemm128<<<dim3(16, 8), 256, 0, stream>>>(E2, 64, ep2f, 64, hid, 1024, 1024,
                                           nullptr, 0, nullptr, T2, counts + 4, 64);

  // projections (dual-write f16 + fp8 x8)
  gemm128<<<dim3(16, 8), 256, 0, stream>>>(hid, 1024, op0T, 1024, ph0, 1024, 1024,
                                           ph0q, 1024, nullptr, nullptr, nullptr, 1024);
  gemm128<<<dim3(16, 2), 256, 0, stream>>>(hid, 1024, op1T, 1024, ph1c, 256, 256,
                                           ph1q, 256, L1, nullptr, counts + 0, 1024);
  gemm128<<<dim3(16, 1), 256, 0, stream>>>(hid, 1024, op2T, 1024, ph2c, 128, 128,
                                           ph2q, 128, L2, nullptr, counts + 1, 1024);

  // fp8 logits + online-LSE partials
  gemm_lse8<<<8 * NCBH, 512, 0, stream>>>(ph0q, headw, headb, nullptr,
                                          pmh, psh, PSTH, 1024, 8);
  gemm_lse8<<<4 * NCBT, 512, 0, stream>>>(ph1q, w1q, b1p, counts + 0,
                                          pm1, ps1, PSTT, 256, 4);
  gemm_lse8<<<4 * NCBT, 512, 0, stream>>>(ph2q, w2q, b2p, counts + 1,
                                          pm2, ps2, PSTT, 128, 4);

  finish_kernel<<<NROWS, 256, 0, stream>>>(ph0, headw, headb, ph1c, w1q, b1p,
                                           ph2c, w2q, b2p, headcol, tailpos, pos1, pos2, cl,
                                           pmh, psh, pm1, ps1, pm2, ps2, out);
}